// Round 1
// baseline (324.417 us; speedup 1.0000x reference)
//
#include <hip/hip_runtime.h>
#include <math.h>

#define S_LEN 1024
#define D_MOD 512
#define NH 8
#define DK 64
#define NB 8

typedef __attribute__((ext_vector_type(8))) short short8;   // 8 bf16 in 4 VGPRs
typedef __attribute__((ext_vector_type(4))) float floatx4;  // MFMA accumulator

union U8 { ushort u[8]; short8 v; };

__device__ __forceinline__ ushort f2bf(float x) {
  unsigned u = __float_as_uint(x);
  unsigned r = (u + 0x7fffu + ((u >> 16) & 1u)) >> 16;  // RNE
  return (ushort)r;
}

// ---------------------------------------------------------------------------
// Fused prep: y=0..2 -> fp32->bf16 convert of q/k/v; y=3 -> mask bit-pack.
// ---------------------------------------------------------------------------
__global__ __launch_bounds__(256) void prep_kern(
    const float* __restrict__ q, const float* __restrict__ k,
    const float* __restrict__ v, const int* __restrict__ smask,
    ushort* __restrict__ qo, ushort* __restrict__ ko,
    ushort* __restrict__ vo, unsigned long long* __restrict__ mb)
{
  const int y = blockIdx.y;
  const int t = threadIdx.x;
  if (y < 3) {
    const float* src = (y == 0) ? q : (y == 1) ? k : v;
    ushort* dst = (y == 0) ? qo : (y == 1) ? ko : vo;
    const int i = blockIdx.x * 256 + t;
    const float4 a = *((const float4*)src + i * 2);
    const float4 b = *((const float4*)src + i * 2 + 1);
    U8 o;
    o.u[0] = f2bf(a.x); o.u[1] = f2bf(a.y); o.u[2] = f2bf(a.z); o.u[3] = f2bf(a.w);
    o.u[4] = f2bf(b.x); o.u[5] = f2bf(b.y); o.u[6] = f2bf(b.z); o.u[7] = f2bf(b.w);
    *(short8*)(dst + (size_t)i * 8) = o.v;
  } else {
    const int row = blockIdx.x * 4 + (t >> 6);
    const int lane = t & 63;
    const int* p = smask + (size_t)row * S_LEN;
    unsigned long long mine = 0;
#pragma unroll
    for (int r = 0; r < 16; ++r) {
      int m = p[r * 64 + lane];
      unsigned long long w = __ballot(m != 0);
      if (lane == r) mine = w;
    }
    if (lane < 16) mb[(size_t)row * 16 + lane] = mine;
  }
}

// ---------------------------------------------------------------------------
// Weight transpose+convert: W fp32 [512(k),512(n)] -> Wt bf16 [512(n),512(k)]
// ---------------------------------------------------------------------------
__global__ __launch_bounds__(256) void wtrans3_kern(
    const float* __restrict__ W0, const float* __restrict__ W1,
    const float* __restrict__ W2, ushort* __restrict__ T0,
    ushort* __restrict__ T1, ushort* __restrict__ T2)
{
  const int z = blockIdx.z;
  const float* W = (z == 0) ? W0 : (z == 1) ? W1 : W2;
  ushort* Wt = (z == 0) ? T0 : (z == 1) ? T1 : T2;
  __shared__ __align__(16) ushort tile[64][72];
  const int t = threadIdx.x;
  const int n0 = blockIdx.x * 64;
  const int k0 = blockIdx.y * 64;
  {
    const int r = t >> 2;
    const int c0 = (t & 3) * 16;
    const float* p = &W[(size_t)(k0 + r) * 512 + n0 + c0];
#pragma unroll
    for (int j = 0; j < 16; ++j) tile[r][c0 + j] = f2bf(p[j]);
  }
  __syncthreads();
  {
    const int c = t >> 2;
    const int kg = (t & 3) * 16;
    U8 lo, hi;
#pragma unroll
    for (int j = 0; j < 8; ++j) lo.u[j] = tile[kg + j][c];
#pragma unroll
    for (int j = 0; j < 8; ++j) hi.u[j] = tile[kg + 8 + j][c];
    ushort* q = &Wt[(size_t)(n0 + c) * 512 + k0 + kg];
    *(short8*)q = lo.v;
    *(short8*)(q + 8) = hi.v;
  }
}

// ---------------------------------------------------------------------------
// bf16 MFMA GEMM, double-buffered B-tile (64n x 64k, XOR-swizzled, 16 KB LDS),
// A wave-private in regs with 2-iter-deep prefetch. Block 128m x 64n, 4 waves
// (32m x 64n each). BK=64, 8 iters, 1 barrier/iter.
// z=0/1: bf16 row-major out. z=2: write Vt [B,H,64,S] directly.
// ---------------------------------------------------------------------------
__global__ __launch_bounds__(256) void gemm_qkv_kern(
    const ushort* __restrict__ qr, const ushort* __restrict__ kr,
    const ushort* __restrict__ vr, const ushort* __restrict__ Wqt,
    const ushort* __restrict__ Wvt, const float* __restrict__ bq,
    const float* __restrict__ bv, ushort* __restrict__ Qo,
    ushort* __restrict__ Ko, ushort* __restrict__ VtO)
{
  __shared__ __align__(16) ushort Bl[2][64][64];

  const int z = blockIdx.z;
  const ushort* A = (z == 0) ? qr : (z == 1) ? kr : vr;
  const ushort* Wt = (z == 2) ? Wvt : Wqt;
  const float* bias = (z == 2) ? bv : bq;

  const int t = threadIdx.x;
  const int w = t >> 6;
  const int lane = t & 63;
  const int quad = lane >> 4;
  const int i16 = lane & 15;
  const int mbase = blockIdx.x * 128 + w * 32;
  const int nbase = blockIdx.y * 64;

  // staging geometry: thread -> B row r, logical chunks lc, lc+1
  const int sr = t >> 2;
  const int slc = (t & 3) * 2;
  const int sp0 = ((slc ^ (sr & 7)) * 8);
  const int sp1 = (((slc + 1) ^ (sr & 7)) * 8);
  const ushort* Bg = Wt + (size_t)(nbase + sr) * 512 + (t & 3) * 16;
  const int xb = i16 & 7;

  const ushort* Ap = A + (size_t)(mbase + i16) * 512 + quad * 8;

  floatx4 acc[2][4];
#pragma unroll
  for (int mi = 0; mi < 2; ++mi)
#pragma unroll
    for (int ni = 0; ni < 4; ++ni) acc[mi][ni] = (floatx4)(0.f);

  short8 areg[3][2][2];  // depth, mi, kc
#pragma unroll
  for (int d = 0; d < 2; ++d)
#pragma unroll
    for (int mi = 0; mi < 2; ++mi)
#pragma unroll
      for (int kc = 0; kc < 2; ++kc)
        areg[d][mi][kc] = *(const short8*)(Ap + d * 64 + kc * 32 + mi * 16 * 512);

  // prologue: stage B tile 0
  {
    short8 b0 = *(const short8*)Bg;
    short8 b1 = *(const short8*)(Bg + 8);
    *(short8*)&Bl[0][sr][sp0] = b0;
    *(short8*)&Bl[0][sr][sp1] = b1;
    __syncthreads();
  }

#pragma unroll
  for (int kt = 0; kt < 8; ++kt) {
    const int cb = kt & 1;
    short8 nb0, nb1;
    if (kt < 7) {
      nb0 = *(const short8*)(Bg + (kt + 1) * 64);
      nb1 = *(const short8*)(Bg + (kt + 1) * 64 + 8);
    }
    if (kt < 6) {
#pragma unroll
      for (int mi = 0; mi < 2; ++mi)
#pragma unroll
        for (int kc = 0; kc < 2; ++kc)
          areg[(kt + 2) % 3][mi][kc] =
              *(const short8*)(Ap + (kt + 2) * 64 + kc * 32 + mi * 16 * 512);
    }
    short8 bf[2][4];
#pragma unroll
    for (int kc = 0; kc < 2; ++kc)
#pragma unroll
      for (int ni = 0; ni < 4; ++ni)
        bf[kc][ni] = *(const short8*)&Bl[cb][ni * 16 + i16][((kc * 4 + quad) ^ xb) * 8];
#pragma unroll
    for (int kc = 0; kc < 2; ++kc)
#pragma unroll
      for (int mi = 0; mi < 2; ++mi)
#pragma unroll
        for (int ni = 0; ni < 4; ++ni)
          acc[mi][ni] = __builtin_amdgcn_mfma_f32_16x16x32_bf16(
              areg[kt % 3][mi][kc], bf[kc][ni], acc[mi][ni], 0, 0, 0);
    if (kt < 7) {
      *(short8*)&Bl[cb ^ 1][sr][sp0] = nb0;
      *(short8*)&Bl[cb ^ 1][sr][sp1] = nb1;
      __syncthreads();
    }
  }

  float bv4[4];
#pragma unroll
  for (int ni = 0; ni < 4; ++ni) bv4[ni] = bias[nbase + ni * 16 + i16];

  if (z < 2) {
    ushort* C = (z == 0) ? Qo : Ko;
#pragma unroll
    for (int mi = 0; mi < 2; ++mi)
#pragma unroll
      for (int ni = 0; ni < 4; ++ni)
#pragma unroll
        for (int r = 0; r < 4; ++r) {
          const int m = mbase + mi * 16 + quad * 4 + r;
          const int n = nbase + ni * 16 + i16;
          C[(size_t)m * 512 + n] = f2bf(acc[mi][ni][r] + bv4[ni]);
        }
  } else {
#pragma unroll
    for (int mi = 0; mi < 2; ++mi)
#pragma unroll
      for (int ni = 0; ni < 4; ++ni) {
        const int m = mbase + mi * 16 + quad * 4;
        const int b = m >> 10;
        const int s = m & 1023;
        const int n = nbase + ni * 16 + i16;
        const int h = n >> 6;
        const int c = n & 63;
        ushort4 pk;
        pk.x = f2bf(acc[mi][ni][0] + bv4[ni]);
        pk.y = f2bf(acc[mi][ni][1] + bv4[ni]);
        pk.z = f2bf(acc[mi][ni][2] + bv4[ni]);
        pk.w = f2bf(acc[mi][ni][3] + bv4[ni]);
        *(ushort4*)(VtO + (((size_t)b * NH + h) * DK + c) * S_LEN + s) = pk;
      }
  }
}

// ---------------------------------------------------------------------------
// Output GEMM: X = Obf @ Wot^T + bo + R (fp32 out). Same dbuf structure.
// ---------------------------------------------------------------------------
__global__ __launch_bounds__(256) void gemm_out_kern(
    const ushort* __restrict__ A, const ushort* __restrict__ Wt,
    const float* __restrict__ bias, const float* __restrict__ R,
    float* __restrict__ X)
{
  __shared__ __align__(16) ushort Bl[2][64][64];

  const int t = threadIdx.x;
  const int w = t >> 6;
  const int lane = t & 63;
  const int quad = lane >> 4;
  const int i16 = lane & 15;
  const int mbase = blockIdx.x * 128 + w * 32;
  const int nbase = blockIdx.y * 64;

  const int sr = t >> 2;
  const int slc = (t & 3) * 2;
  const int sp0 = ((slc ^ (sr & 7)) * 8);
  const int sp1 = (((slc + 1) ^ (sr & 7)) * 8);
  const ushort* Bg = Wt + (size_t)(nbase + sr) * 512 + (t & 3) * 16;
  const int xb = i16 & 7;

  const ushort* Ap = A + (size_t)(mbase + i16) * 512 + quad * 8;

  floatx4 acc[2][4];
#pragma unroll
  for (int mi = 0; mi < 2; ++mi)
#pragma unroll
    for (int ni = 0; ni < 4; ++ni) acc[mi][ni] = (floatx4)(0.f);

  short8 areg[3][2][2];
#pragma unroll
  for (int d = 0; d < 2; ++d)
#pragma unroll
    for (int mi = 0; mi < 2; ++mi)
#pragma unroll
      for (int kc = 0; kc < 2; ++kc)
        areg[d][mi][kc] = *(const short8*)(Ap + d * 64 + kc * 32 + mi * 16 * 512);

  {
    short8 b0 = *(const short8*)Bg;
    short8 b1 = *(const short8*)(Bg + 8);
    *(short8*)&Bl[0][sr][sp0] = b0;
    *(short8*)&Bl[0][sr][sp1] = b1;
    __syncthreads();
  }

#pragma unroll
  for (int kt = 0; kt < 8; ++kt) {
    const int cb = kt & 1;
    short8 nb0, nb1;
    if (kt < 7) {
      nb0 = *(const short8*)(Bg + (kt + 1) * 64);
      nb1 = *(const short8*)(Bg + (kt + 1) * 64 + 8);
    }
    if (kt < 6) {
#pragma unroll
      for (int mi = 0; mi < 2; ++mi)
#pragma unroll
        for (int kc = 0; kc < 2; ++kc)
          areg[(kt + 2) % 3][mi][kc] =
              *(const short8*)(Ap + (kt + 2) * 64 + kc * 32 + mi * 16 * 512);
    }
    short8 bf[2][4];
#pragma unroll
    for (int kc = 0; kc < 2; ++kc)
#pragma unroll
      for (int ni = 0; ni < 4; ++ni)
        bf[kc][ni] = *(const short8*)&Bl[cb][ni * 16 + i16][((kc * 4 + quad) ^ xb) * 8];
#pragma unroll
    for (int kc = 0; kc < 2; ++kc)
#pragma unroll
      for (int mi = 0; mi < 2; ++mi)
#pragma unroll
        for (int ni = 0; ni < 4; ++ni)
          acc[mi][ni] = __builtin_amdgcn_mfma_f32_16x16x32_bf16(
              areg[kt % 3][mi][kc], bf[kc][ni], acc[mi][ni], 0, 0, 0);
    if (kt < 7) {
      *(short8*)&Bl[cb ^ 1][sr][sp0] = nb0;
      *(short8*)&Bl[cb ^ 1][sr][sp1] = nb1;
      __syncthreads();
    }
  }

  float bv4[4];
#pragma unroll
  for (int ni = 0; ni < 4; ++ni) bv4[ni] = bias[nbase + ni * 16 + i16];
#pragma unroll
  for (int mi = 0; mi < 2; ++mi)
#pragma unroll
    for (int ni = 0; ni < 4; ++ni)
#pragma unroll
      for (int r = 0; r < 4; ++r) {
        const int m = mbase + mi * 16 + quad * 4 + r;
        const int n = nbase + ni * 16 + i16;
        X[(size_t)m * 512 + n] = acc[mi][ni][r] + bv4[ni] + R[(size_t)m * 512 + n];
      }
}

// ---------------------------------------------------------------------------
// MFMA dual-score causal attention, K-SPLIT 8-wave blocks (512 threads).
// Waves 0-3 (group 0) process even k-tiles, waves 4-7 (group 1) odd k-tiles,
// for the same four 16-row q-strips. O/l are plain sums over k (no online
// max), so the k-split is associative: partials combine through LDS scratch
// (reusing the dead K buffers) at seg end. Seg-pairing (p, 15-p) keeps every
// block at exactly 9(A)/8(B) k-tile iterations -> perfect balance.
// LDS: single-buffered K/Kr/V per group (2 x 24 KB) + Pl (16 KB) = 64 KB
// -> 2 blocks/CU -> 16 waves/CU (2x the old dbuf layout's 8). Single-buffer
// costs 2 barriers/iter, hidden by the reg-prefetch (next tile's global
// loads issue before compute, ds_writes land after the barrier).
// ---------------------------------------------------------------------------
__global__ __launch_bounds__(512, 4) void attn_kern(
    const ushort* __restrict__ Qb, const ushort* __restrict__ Kb,
    const ushort* __restrict__ VtG, const ushort* __restrict__ qraw,
    const ushort* __restrict__ kraw,
    const unsigned long long* __restrict__ mbits,
    const float* __restrict__ gammas, ushort* __restrict__ Obf)
{
  __shared__ __align__(16) ushort Kp[2][64][64];   // [group][k][d]
  __shared__ __align__(16) ushort Kr[2][64][64];
  __shared__ __align__(16) ushort Vc[2][64][64];
  __shared__ __align__(16) ushort Pl[8][16][64];   // per-wave P staging

  const int t = threadIdx.x;
  const int w = t >> 6;          // 0..7
  const int grp = w >> 2;        // k-parity group: handles kt == grp (mod 2)
  const int ws = w & 3;          // q-strip within the 64-row q-tile
  const int lane = t & 63;
  const int quad = lane >> 4;
  const int i16 = lane & 15;
  const int bh = blockIdx.x;     // 0..63
  const int b = bh >> 3;
  const int h = bh & 7;
  const int p = blockIdx.y;      // 0..7

  const float gam = gammas[h];
  float te = __expf(-log1pf(__expf(gam)));
  te = fminf(fmaxf(te, 1e-5f), 1e5f);
  const float c1 = 0.125f * 1.44269504f;
  const float c2 = te * 0.044194173824159216f * 1.44269504f;

  const int xi = i16 & 7;
  const int tg = t & 255;             // thread id within group
  const int rr = tg >> 3;             // staging row 0..31
  const int lc = tg & 7;
  const int pc = ((lc ^ (rr & 7)) * 8);

  const ushort* kpgB = Kb + ((size_t)b * S_LEN + rr) * D_MOD + h * DK + lc * 8;
  const ushort* krgB = kraw + ((size_t)b * S_LEN + rr) * D_MOD + h * DK + lc * 8;
  const ushort* vgB  = VtG + ((size_t)bh * DK + rr) * S_LEN + lc * 8;

  float* const scrO = (float*)&Kp[0][0][0];   // 16 KB combine scratch (dead K)
  float* const scrL = (float*)&Kr[0][0][0];   // 4 KB

#pragma unroll
  for (int seg = 0; seg < 2; ++seg) {
    const int qt = seg ? (15 - p) : p;
    const int qbase = qt * 64 + ws * 16;
    const int nit = qt + 1;
    const int L = (nit + 1) >> 1;   // per-group iteration count (uniform)

    short8 Qp[2], Qr[2];
    {
      const ushort* qp = Qb + ((size_t)b * S_LEN + qbase + i16) * D_MOD + h * DK + quad * 8;
      const ushort* qq = qraw + ((size_t)b * S_LEN + qbase + i16) * D_MOD + h * DK + quad * 8;
#pragma unroll
      for (int s = 0; s < 2; ++s) {
        Qp[s] = *(const short8*)(qp + s * 32);
        Qr[s] = *(const short8*)(qq + s * 32);
      }
    }

    floatx4 Oacc[4];
#pragma unroll
    for (int t4 = 0; t4 < 4; ++t4) Oacc[t4] = (floatx4)(0.f);
    float l_run[4] = {0.f, 0.f, 0.f, 0.f};

    // ---- prologue: stage this group's first tile (kt = grp) ----
    {
      short8 s0, s1, s2, s3, s4, s5;
      const bool have0 = (grp < nit);
      if (have0) {
        const size_t ko = (size_t)grp * 64;
        s0 = *(const short8*)(kpgB + ko * D_MOD);
        s1 = *(const short8*)(kpgB + ko * D_MOD + 32 * D_MOD);
        s2 = *(const short8*)(krgB + ko * D_MOD);
        s3 = *(const short8*)(krgB + ko * D_MOD + 32 * D_MOD);
        s4 = *(const short8*)(vgB + ko);
        s5 = *(const short8*)(vgB + ko + 32 * S_LEN);
      }
      __syncthreads();   // prior seg's LDS readers (incl. combine) done
      if (have0) {
        *(short8*)&Kp[grp][rr][pc] = s0;
        *(short8*)&Kp[grp][rr + 32][pc] = s1;
        *(short8*)&Kr[grp][rr][pc] = s2;
        *(short8*)&Kr[grp][rr + 32][pc] = s3;
        *(short8*)&Vc[grp][rr][pc] = s4;
        *(short8*)&Vc[grp][rr + 32][pc] = s5;
      }
      __syncthreads();
    }

    for (int it = 0; it < L; ++it) {
      const int kt = grp + 2 * it;
      const bool active = (kt < nit);          // group 1 may idle on last it
      const bool havenext = (kt + 2 < nit);
      const bool diag = (kt == qt);

      // ---- prefetch this group's next tile (global -> regs) ----
      short8 nk0, nk1, nr0, nr1, nv0, nv1;
      if (havenext) {
        const size_t ko = (size_t)(kt + 2) * 64;
        nk0 = *(const short8*)(kpgB + ko * D_MOD);
        nk1 = *(const short8*)(kpgB + ko * D_MOD + 32 * D_MOD);
        nr0 = *(const short8*)(krgB + ko * D_MOD);
        nr1 = *(const short8*)(krgB + ko * D_MOD + 32 * D_MOD);
        nv0 = *(const short8*)(vgB + ko);
        nv1 = *(const short8*)(vgB + ko + 32 * S_LEN);
      }

      if (active) {
        unsigned long long mw[4];
#pragma unroll
        for (int r = 0; r < 4; ++r)
          mw[r] = mbits[((size_t)b * S_LEN + qbase + quad * 4 + r) * 16 + kt];

        // ---- scores: 16 MFMAs from LDS ----
        floatx4 accp[4], accr[4];
#pragma unroll
        for (int t4 = 0; t4 < 4; ++t4) { accp[t4] = (floatx4)(0.f); accr[t4] = (floatx4)(0.f); }
#pragma unroll
        for (int s = 0; s < 2; ++s) {
          const int co = ((s * 4 + quad) ^ xi) * 8;
          short8 kp4[4], kr4[4];
#pragma unroll
          for (int t4 = 0; t4 < 4; ++t4) kp4[t4] = *(const short8*)&Kp[grp][t4 * 16 + i16][co];
#pragma unroll
          for (int t4 = 0; t4 < 4; ++t4) kr4[t4] = *(const short8*)&Kr[grp][t4 * 16 + i16][co];
#pragma unroll
          for (int t4 = 0; t4 < 4; ++t4)
            accp[t4] = __builtin_amdgcn_mfma_f32_16x16x32_bf16(Qp[s], kp4[t4], accp[t4], 0, 0, 0);
#pragma unroll
          for (int t4 = 0; t4 < 4; ++t4)
            accr[t4] = __builtin_amdgcn_mfma_f32_16x16x32_bf16(Qr[s], kr4[t4], accr[t4], 0, 0, 0);
        }

        // ---- combine + exp2, P -> per-wave LDS (truncation pack) ----
        const int k0g = kt * 64;
#pragma unroll
        for (int r = 0; r < 4; ++r) {
          const int qg = qbase + quad * 4 + r;
          const int prow = quad * 4 + r;
#pragma unroll
          for (int t4 = 0; t4 < 4; ++t4) {
            const float bitf = ((mw[r] >> (t4 * 16 + i16)) & 1ULL) ? c2 : 0.f;
            const float sv = accp[t4][r] * c1 + accr[t4][r] * bitf;
            float pv = __builtin_amdgcn_exp2f(sv);
            if (diag) {
              const int kg = k0g + t4 * 16 + i16;
              pv = (kg < qg) ? pv : 0.f;
            }
            l_run[r] += pv;
            const int kc = t4 * 2 + (i16 >> 3);
            Pl[w][prow][((kc ^ (prow & 7)) * 8) + (i16 & 7)] =
                (ushort)(__float_as_uint(pv) >> 16);
          }
        }

        // ---- PV: 8 MFMAs ----
#pragma unroll
        for (int s = 0; s < 2; ++s) {
          const int co = ((s * 4 + quad) ^ xi) * 8;
          short8 a = *(const short8*)&Pl[w][i16][co];
#pragma unroll
          for (int t4 = 0; t4 < 4; ++t4) {
            short8 bv8 = *(const short8*)&Vc[grp][t4 * 16 + i16][co];
            Oacc[t4] = __builtin_amdgcn_mfma_f32_16x16x32_bf16(a, bv8, Oacc[t4], 0, 0, 0);
          }
        }
      }

      __syncthreads();               // group's readers done with LDS tile
      if (havenext) {
        *(short8*)&Kp[grp][rr][pc] = nk0;
        *(short8*)&Kp[grp][rr + 32][pc] = nk1;
        *(short8*)&Kr[grp][rr][pc] = nr0;
        *(short8*)&Kr[grp][rr + 32][pc] = nr1;
        *(short8*)&Vc[grp][rr][pc] = nv0;
        *(short8*)&Vc[grp][rr + 32][pc] = nv1;
      }
      __syncthreads();               // next tile visible
    }

    // ---- cross-group combine (K buffers dead) + epilogue by group 0 ----
    if (grp == 1) {
#pragma unroll
      for (int t4 = 0; t4 < 4; ++t4)
#pragma unroll
        for (int r = 0; r < 4; ++r)
          scrO[(t4 * 4 + r) * 256 + tg] = Oacc[t4][r];
#pragma unroll
      for (int r = 0; r < 4; ++r) scrL[r * 256 + tg] = l_run[r];
    }
    __syncthreads();
    if (grp == 0) {
#pragma unroll
      for (int t4 = 0; t4 < 4; ++t4)
#pragma unroll
        for (int r = 0; r < 4; ++r)
          Oacc[t4][r] += scrO[(t4 * 4 + r) * 256 + tg];
#pragma unroll
      for (int r = 0; r < 4; ++r) {
        float l = l_run[r] + scrL[r * 256 + tg];
#pragma unroll
        for (int off = 1; off < 16; off <<= 1) l += __shfl_xor(l, off);
        const float inv = (l > 0.f) ? 1.f / l : 0.f;
        ushort* orow = Obf + ((size_t)b * S_LEN + qbase + quad * 4 + r) * D_MOD + h * DK;
#pragma unroll
        for (int t4 = 0; t4 < 4; ++t4)
          orow[t4 * 16 + i16] = f2bf(Oacc[t4][r] * inv);
      }
    }
    // next seg's prologue barrier orders scratch reads vs. re-staging
  }
}

// ---------------------------------------------------------------------------
// LayerNorm over D=512, one wave per row.
// ---------------------------------------------------------------------------
__global__ __launch_bounds__(256) void ln_kern(
    const float* __restrict__ X, const float* __restrict__ gw,
    const float* __restrict__ bw, float* __restrict__ out)
{
  const int row = blockIdx.x * 4 + (threadIdx.x >> 6);
  const int lane = threadIdx.x & 63;
  const int c = lane * 8;
  const float* xp = &X[(size_t)row * D_MOD + c];
  const float4 x0 = *(const float4*)xp;
  const float4 x1 = *(const float4*)(xp + 4);
  float xv[8] = {x0.x, x0.y, x0.z, x0.w, x1.x, x1.y, x1.z, x1.w};
  float sum = 0.f;
#pragma unroll
  for (int u = 0; u < 8; ++u) sum += xv[u];
#pragma unroll
  for (int off = 1; off < 64; off <<= 1) sum += __shfl_xor(sum, off, 64);
  const float mu = sum * (1.f / 512.f);
  float ss = 0.f;
#pragma unroll
  for (int u = 0; u < 8; ++u) { xv[u] -= mu; ss += xv[u] * xv[u]; }
#pragma unroll
  for (int off = 1; off < 64; off <<= 1) ss += __shfl_xor(ss, off, 64);
  const float rstd = rsqrtf(ss * (1.f / 512.f) + 1e-5f);
  const float4 g0 = *(const float4*)&gw[c];
  const float4 g1 = *(const float4*)&gw[c + 4];
  const float4 b0 = *(const float4*)&bw[c];
  const float4 b1 = *(const float4*)&bw[c + 4];
  float* op = &out[(size_t)row * D_MOD + c];
  *(float4*)op = make_float4(xv[0] * rstd * g0.x + b0.x,
                             xv[1] * rstd * g0.y + b0.y,
                             xv[2] * rstd * g0.z + b0.z,
                             xv[3] * rstd * g0.w + b0.w);
  *(float4*)(op + 4) = make_float4(xv[4] * rstd * g1.x + b1.x,
                                   xv[5] * rstd * g1.y + b1.y,
                                   xv[6] * rstd * g1.z + b1.z,
                                   xv[7] * rstd * g1.w + b1.w);
}

// ---------------------------------------------------------------------------
extern "C" void kernel_launch(void* const* d_in, const int* in_sizes, int n_in,
                              void* d_out, int out_size, void* d_ws, size_t ws_size,
                              hipStream_t stream)
{
  const float* q_in  = (const float*)d_in[0];
  const float* k_in  = (const float*)d_in[1];
  const float* v_in  = (const float*)d_in[2];
  const int*   smask = (const int*)d_in[3];
  const float* Wq = (const float*)d_in[4];
  const float* bq = (const float*)d_in[5];
  const float* Wv = (const float*)d_in[6];
  const float* bv = (const float*)d_in[7];
  const float* Wo = (const float*)d_in[8];
  const float* bo = (const float*)d_in[9];
  const float* gammas = (const float*)d_in[10];
  const float* ln_g = (const float*)d_in[11];
  const float* ln_b = (const float*)d_in[12];
  float* out = (float*)d_out;

  char* ws = (char*)d_ws;
  const size_t BF = (size_t)NB * S_LEN * D_MOD * sizeof(ushort);  // 8 MiB
  ushort* qr  = (ushort*)(ws);                 // [0,8M)
  ushort* kr  = (ushort*)(ws + BF);            // [8M,16M)
  ushort* vr  = (ushort*)(ws + 2 * BF);        // [16M,24M); Obf overlays after V-GEMM
  ushort* Obf = (ushort*)(ws + 2 * BF);
  ushort* Qbf = (ushort*)(ws + 3 * BF);        // [24M,32M)
  ushort* Kbf = (ushort*)(ws + 4 * BF);        // [32M,40M)
  ushort* Vt  = (ushort*)(ws + 5 * BF);        // [40M,48M)
  unsigned long long* mbits = (unsigned long long*)(ws + 6 * BF);      // 1 MiB
  ushort* Wqt = (ushort*)(ws + 6 * BF + (1 << 20));                    // 512 KiB
  ushort* Wvt = Wqt + 512 * 512;
  ushort* Wot = Wvt + 512 * 512;
  float*  X   = (float*)ws;                    // overlays qr+kr (dead after attn)

  const dim3 tb(256);

  prep_kern<<<dim3(2048, 4), tb, 0, stream>>>(q_in, k_in, v_in, smask,
                                              qr, kr, vr, mbits);
  wtrans3_kern<<<dim3(8, 8, 3), tb, 0, stream>>>(Wq, Wv, Wo, Wqt, Wvt, Wot);

  gemm_qkv_kern<<<dim3(64, 8, 3), tb, 0, stream>>>(qr, kr, vr, Wqt, Wvt,
                                                   bq, bv, Qbf, Kbf, Vt);

  attn_kern<<<dim3(64, 8), dim3(512), 0, stream>>>(Qbf, Kbf, Vt, qr, kr, mbits,
                                                   gammas, Obf);

  gemm_out_kern<<<dim3(64, 8), tb, 0, stream>>>(Obf, Wot, bo, q_in, X);
  ln_kern<<<2048, tb, 0, stream>>>(X, ln_g, ln_b, out);
}

// Round 2
// 242.728 us; speedup vs baseline: 1.3365x; 1.3365x over previous
//
#include <hip/hip_runtime.h>
#include <math.h>

#define S_LEN 1024
#define D_MOD 512
#define NH 8
#define DK 64
#define NB 8

typedef __attribute__((ext_vector_type(8))) short short8;   // 8 bf16 in 4 VGPRs
typedef __attribute__((ext_vector_type(4))) float floatx4;  // MFMA accumulator

union U8 { ushort u[8]; short8 v; };

__device__ __forceinline__ ushort f2bf(float x) {
  unsigned u = __float_as_uint(x);
  unsigned r = (u + 0x7fffu + ((u >> 16) & 1u)) >> 16;  // RNE
  return (ushort)r;
}

// ---------------------------------------------------------------------------
// Fused prep: y=0..2 -> fp32->bf16 convert of q/k/v; y=3 -> mask bit-pack.
// ---------------------------------------------------------------------------
__global__ __launch_bounds__(256) void prep_kern(
    const float* __restrict__ q, const float* __restrict__ k,
    const float* __restrict__ v, const int* __restrict__ smask,
    ushort* __restrict__ qo, ushort* __restrict__ ko,
    ushort* __restrict__ vo, unsigned long long* __restrict__ mb)
{
  const int y = blockIdx.y;
  const int t = threadIdx.x;
  if (y < 3) {
    const float* src = (y == 0) ? q : (y == 1) ? k : v;
    ushort* dst = (y == 0) ? qo : (y == 1) ? ko : vo;
    const int i = blockIdx.x * 256 + t;
    const float4 a = *((const float4*)src + i * 2);
    const float4 b = *((const float4*)src + i * 2 + 1);
    U8 o;
    o.u[0] = f2bf(a.x); o.u[1] = f2bf(a.y); o.u[2] = f2bf(a.z); o.u[3] = f2bf(a.w);
    o.u[4] = f2bf(b.x); o.u[5] = f2bf(b.y); o.u[6] = f2bf(b.z); o.u[7] = f2bf(b.w);
    *(short8*)(dst + (size_t)i * 8) = o.v;
  } else {
    const int row = blockIdx.x * 4 + (t >> 6);
    const int lane = t & 63;
    const int* p = smask + (size_t)row * S_LEN;
    unsigned long long mine = 0;
#pragma unroll
    for (int r = 0; r < 16; ++r) {
      int m = p[r * 64 + lane];
      unsigned long long w = __ballot(m != 0);
      if (lane == r) mine = w;
    }
    if (lane < 16) mb[(size_t)row * 16 + lane] = mine;
  }
}

// ---------------------------------------------------------------------------
// Weight transpose+convert: W fp32 [512(k),512(n)] -> Wt bf16 [512(n),512(k)]
// ---------------------------------------------------------------------------
__global__ __launch_bounds__(256) void wtrans3_kern(
    const float* __restrict__ W0, const float* __restrict__ W1,
    const float* __restrict__ W2, ushort* __restrict__ T0,
    ushort* __restrict__ T1, ushort* __restrict__ T2)
{
  const int z = blockIdx.z;
  const float* W = (z == 0) ? W0 : (z == 1) ? W1 : W2;
  ushort* Wt = (z == 0) ? T0 : (z == 1) ? T1 : T2;
  __shared__ __align__(16) ushort tile[64][72];
  const int t = threadIdx.x;
  const int n0 = blockIdx.x * 64;
  const int k0 = blockIdx.y * 64;
  {
    const int r = t >> 2;
    const int c0 = (t & 3) * 16;
    const float* p = &W[(size_t)(k0 + r) * 512 + n0 + c0];
#pragma unroll
    for (int j = 0; j < 16; ++j) tile[r][c0 + j] = f2bf(p[j]);
  }
  __syncthreads();
  {
    const int c = t >> 2;
    const int kg = (t & 3) * 16;
    U8 lo, hi;
#pragma unroll
    for (int j = 0; j < 8; ++j) lo.u[j] = tile[kg + j][c];
#pragma unroll
    for (int j = 0; j < 8; ++j) hi.u[j] = tile[kg + 8 + j][c];
    ushort* q = &Wt[(size_t)(n0 + c) * 512 + k0 + kg];
    *(short8*)q = lo.v;
    *(short8*)(q + 8) = hi.v;
  }
}

// ---------------------------------------------------------------------------
// bf16 MFMA GEMM, double-buffered B-tile (64n x 64k, XOR-swizzled, 16 KB LDS),
// A wave-private in regs with 2-iter-deep prefetch. Block 128m x 64n, 4 waves
// (32m x 64n each). BK=64, 8 iters, 1 barrier/iter.
// z=0/1: bf16 row-major out. z=2: write Vt [B,H,64,S] directly.
// ---------------------------------------------------------------------------
__global__ __launch_bounds__(256) void gemm_qkv_kern(
    const ushort* __restrict__ qr, const ushort* __restrict__ kr,
    const ushort* __restrict__ vr, const ushort* __restrict__ Wqt,
    const ushort* __restrict__ Wvt, const float* __restrict__ bq,
    const float* __restrict__ bv, ushort* __restrict__ Qo,
    ushort* __restrict__ Ko, ushort* __restrict__ VtO)
{
  __shared__ __align__(16) ushort Bl[2][64][64];

  const int z = blockIdx.z;
  const ushort* A = (z == 0) ? qr : (z == 1) ? kr : vr;
  const ushort* Wt = (z == 2) ? Wvt : Wqt;
  const float* bias = (z == 2) ? bv : bq;

  const int t = threadIdx.x;
  const int w = t >> 6;
  const int lane = t & 63;
  const int quad = lane >> 4;
  const int i16 = lane & 15;
  const int mbase = blockIdx.x * 128 + w * 32;
  const int nbase = blockIdx.y * 64;

  // staging geometry: thread -> B row r, logical chunks lc, lc+1
  const int sr = t >> 2;
  const int slc = (t & 3) * 2;
  const int sp0 = ((slc ^ (sr & 7)) * 8);
  const int sp1 = (((slc + 1) ^ (sr & 7)) * 8);
  const ushort* Bg = Wt + (size_t)(nbase + sr) * 512 + (t & 3) * 16;
  const int xb = i16 & 7;

  const ushort* Ap = A + (size_t)(mbase + i16) * 512 + quad * 8;

  floatx4 acc[2][4];
#pragma unroll
  for (int mi = 0; mi < 2; ++mi)
#pragma unroll
    for (int ni = 0; ni < 4; ++ni) acc[mi][ni] = (floatx4)(0.f);

  short8 areg[3][2][2];  // depth, mi, kc
#pragma unroll
  for (int d = 0; d < 2; ++d)
#pragma unroll
    for (int mi = 0; mi < 2; ++mi)
#pragma unroll
      for (int kc = 0; kc < 2; ++kc)
        areg[d][mi][kc] = *(const short8*)(Ap + d * 64 + kc * 32 + mi * 16 * 512);

  // prologue: stage B tile 0
  {
    short8 b0 = *(const short8*)Bg;
    short8 b1 = *(const short8*)(Bg + 8);
    *(short8*)&Bl[0][sr][sp0] = b0;
    *(short8*)&Bl[0][sr][sp1] = b1;
    __syncthreads();
  }

#pragma unroll
  for (int kt = 0; kt < 8; ++kt) {
    const int cb = kt & 1;
    short8 nb0, nb1;
    if (kt < 7) {
      nb0 = *(const short8*)(Bg + (kt + 1) * 64);
      nb1 = *(const short8*)(Bg + (kt + 1) * 64 + 8);
    }
    if (kt < 6) {
#pragma unroll
      for (int mi = 0; mi < 2; ++mi)
#pragma unroll
        for (int kc = 0; kc < 2; ++kc)
          areg[(kt + 2) % 3][mi][kc] =
              *(const short8*)(Ap + (kt + 2) * 64 + kc * 32 + mi * 16 * 512);
    }
    short8 bf[2][4];
#pragma unroll
    for (int kc = 0; kc < 2; ++kc)
#pragma unroll
      for (int ni = 0; ni < 4; ++ni)
        bf[kc][ni] = *(const short8*)&Bl[cb][ni * 16 + i16][((kc * 4 + quad) ^ xb) * 8];
#pragma unroll
    for (int kc = 0; kc < 2; ++kc)
#pragma unroll
      for (int mi = 0; mi < 2; ++mi)
#pragma unroll
        for (int ni = 0; ni < 4; ++ni)
          acc[mi][ni] = __builtin_amdgcn_mfma_f32_16x16x32_bf16(
              areg[kt % 3][mi][kc], bf[kc][ni], acc[mi][ni], 0, 0, 0);
    if (kt < 7) {
      *(short8*)&Bl[cb ^ 1][sr][sp0] = nb0;
      *(short8*)&Bl[cb ^ 1][sr][sp1] = nb1;
      __syncthreads();
    }
  }

  float bv4[4];
#pragma unroll
  for (int ni = 0; ni < 4; ++ni) bv4[ni] = bias[nbase + ni * 16 + i16];

  if (z < 2) {
    ushort* C = (z == 0) ? Qo : Ko;
#pragma unroll
    for (int mi = 0; mi < 2; ++mi)
#pragma unroll
      for (int ni = 0; ni < 4; ++ni)
#pragma unroll
        for (int r = 0; r < 4; ++r) {
          const int m = mbase + mi * 16 + quad * 4 + r;
          const int n = nbase + ni * 16 + i16;
          C[(size_t)m * 512 + n] = f2bf(acc[mi][ni][r] + bv4[ni]);
        }
  } else {
#pragma unroll
    for (int mi = 0; mi < 2; ++mi)
#pragma unroll
      for (int ni = 0; ni < 4; ++ni) {
        const int m = mbase + mi * 16 + quad * 4;
        const int b = m >> 10;
        const int s = m & 1023;
        const int n = nbase + ni * 16 + i16;
        const int h = n >> 6;
        const int c = n & 63;
        ushort4 pk;
        pk.x = f2bf(acc[mi][ni][0] + bv4[ni]);
        pk.y = f2bf(acc[mi][ni][1] + bv4[ni]);
        pk.z = f2bf(acc[mi][ni][2] + bv4[ni]);
        pk.w = f2bf(acc[mi][ni][3] + bv4[ni]);
        *(ushort4*)(VtO + (((size_t)b * NH + h) * DK + c) * S_LEN + s) = pk;
      }
  }
}

// ---------------------------------------------------------------------------
// Output GEMM: X = Obf @ Wot^T + bo + R (fp32 out). Same dbuf structure.
// ---------------------------------------------------------------------------
__global__ __launch_bounds__(256) void gemm_out_kern(
    const ushort* __restrict__ A, const ushort* __restrict__ Wt,
    const float* __restrict__ bias, const float* __restrict__ R,
    float* __restrict__ X)
{
  __shared__ __align__(16) ushort Bl[2][64][64];

  const int t = threadIdx.x;
  const int w = t >> 6;
  const int lane = t & 63;
  const int quad = lane >> 4;
  const int i16 = lane & 15;
  const int mbase = blockIdx.x * 128 + w * 32;
  const int nbase = blockIdx.y * 64;

  const int sr = t >> 2;
  const int slc = (t & 3) * 2;
  const int sp0 = ((slc ^ (sr & 7)) * 8);
  const int sp1 = (((slc + 1) ^ (sr & 7)) * 8);
  const ushort* Bg = Wt + (size_t)(nbase + sr) * 512 + (t & 3) * 16;
  const int xb = i16 & 7;

  const ushort* Ap = A + (size_t)(mbase + i16) * 512 + quad * 8;

  floatx4 acc[2][4];
#pragma unroll
  for (int mi = 0; mi < 2; ++mi)
#pragma unroll
    for (int ni = 0; ni < 4; ++ni) acc[mi][ni] = (floatx4)(0.f);

  short8 areg[3][2][2];
#pragma unroll
  for (int d = 0; d < 2; ++d)
#pragma unroll
    for (int mi = 0; mi < 2; ++mi)
#pragma unroll
      for (int kc = 0; kc < 2; ++kc)
        areg[d][mi][kc] = *(const short8*)(Ap + d * 64 + kc * 32 + mi * 16 * 512);

  {
    short8 b0 = *(const short8*)Bg;
    short8 b1 = *(const short8*)(Bg + 8);
    *(short8*)&Bl[0][sr][sp0] = b0;
    *(short8*)&Bl[0][sr][sp1] = b1;
    __syncthreads();
  }

#pragma unroll
  for (int kt = 0; kt < 8; ++kt) {
    const int cb = kt & 1;
    short8 nb0, nb1;
    if (kt < 7) {
      nb0 = *(const short8*)(Bg + (kt + 1) * 64);
      nb1 = *(const short8*)(Bg + (kt + 1) * 64 + 8);
    }
    if (kt < 6) {
#pragma unroll
      for (int mi = 0; mi < 2; ++mi)
#pragma unroll
        for (int kc = 0; kc < 2; ++kc)
          areg[(kt + 2) % 3][mi][kc] =
              *(const short8*)(Ap + (kt + 2) * 64 + kc * 32 + mi * 16 * 512);
    }
    short8 bf[2][4];
#pragma unroll
    for (int kc = 0; kc < 2; ++kc)
#pragma unroll
      for (int ni = 0; ni < 4; ++ni)
        bf[kc][ni] = *(const short8*)&Bl[cb][ni * 16 + i16][((kc * 4 + quad) ^ xb) * 8];
#pragma unroll
    for (int kc = 0; kc < 2; ++kc)
#pragma unroll
      for (int mi = 0; mi < 2; ++mi)
#pragma unroll
        for (int ni = 0; ni < 4; ++ni)
          acc[mi][ni] = __builtin_amdgcn_mfma_f32_16x16x32_bf16(
              areg[kt % 3][mi][kc], bf[kc][ni], acc[mi][ni], 0, 0, 0);
    if (kt < 7) {
      *(short8*)&Bl[cb ^ 1][sr][sp0] = nb0;
      *(short8*)&Bl[cb ^ 1][sr][sp1] = nb1;
      __syncthreads();
    }
  }

  float bv4[4];
#pragma unroll
  for (int ni = 0; ni < 4; ++ni) bv4[ni] = bias[nbase + ni * 16 + i16];
#pragma unroll
  for (int mi = 0; mi < 2; ++mi)
#pragma unroll
    for (int ni = 0; ni < 4; ++ni)
#pragma unroll
      for (int r = 0; r < 4; ++r) {
        const int m = mbase + mi * 16 + quad * 4 + r;
        const int n = nbase + ni * 16 + i16;
        X[(size_t)m * 512 + n] = acc[mi][ni][r] + bv4[ni] + R[(size_t)m * 512 + n];
      }
}

// ---------------------------------------------------------------------------
// MFMA dual-score causal attention, K-SPLIT 8-wave blocks (512 threads).
// Waves 0-3 (group 0) process even k-tiles, waves 4-7 (group 1) odd k-tiles,
// for the same four 16-row q-strips. O/l are plain sums over k (no online
// max), so the k-split is associative: partials combine through LDS scratch
// (reusing the dead K buffers) at seg end. Seg-pairing (p, 15-p) keeps every
// block at exactly 9(A)/8(B) k-tile iterations -> perfect balance.
// LDS: single-buffered K/Kr/V per group (2 x 24 KB) + Pl (16 KB) = 64 KB
// -> 2 blocks/CU -> 16 waves/CU. NOTE (R1 post-mortem): __launch_bounds__
// min-waves clause forced VGPR=64 -> 480 MB of spill traffic, 3x regression.
// Plain __launch_bounds__(512): compiler allocates ~116-150 VGPR, no spill;
// occupancy is LDS-limited at 2 blocks/CU which is all we need.
// ---------------------------------------------------------------------------
__global__ __launch_bounds__(512) void attn_kern(
    const ushort* __restrict__ Qb, const ushort* __restrict__ Kb,
    const ushort* __restrict__ VtG, const ushort* __restrict__ qraw,
    const ushort* __restrict__ kraw,
    const unsigned long long* __restrict__ mbits,
    const float* __restrict__ gammas, ushort* __restrict__ Obf)
{
  __shared__ __align__(16) ushort Kp[2][64][64];   // [group][k][d]
  __shared__ __align__(16) ushort Kr[2][64][64];
  __shared__ __align__(16) ushort Vc[2][64][64];
  __shared__ __align__(16) ushort Pl[8][16][64];   // per-wave P staging

  const int t = threadIdx.x;
  const int w = t >> 6;          // 0..7
  const int grp = w >> 2;        // k-parity group: handles kt == grp (mod 2)
  const int ws = w & 3;          // q-strip within the 64-row q-tile
  const int lane = t & 63;
  const int quad = lane >> 4;
  const int i16 = lane & 15;
  const int bh = blockIdx.x;     // 0..63
  const int b = bh >> 3;
  const int h = bh & 7;
  const int p = blockIdx.y;      // 0..7

  const float gam = gammas[h];
  float te = __expf(-log1pf(__expf(gam)));
  te = fminf(fmaxf(te, 1e-5f), 1e5f);
  const float c1 = 0.125f * 1.44269504f;
  const float c2 = te * 0.044194173824159216f * 1.44269504f;

  const int xi = i16 & 7;
  const int tg = t & 255;             // thread id within group
  const int rr = tg >> 3;             // staging row 0..31
  const int lc = tg & 7;
  const int pc = ((lc ^ (rr & 7)) * 8);

  const ushort* kpgB = Kb + ((size_t)b * S_LEN + rr) * D_MOD + h * DK + lc * 8;
  const ushort* krgB = kraw + ((size_t)b * S_LEN + rr) * D_MOD + h * DK + lc * 8;
  const ushort* vgB  = VtG + ((size_t)bh * DK + rr) * S_LEN + lc * 8;

  float* const scrO = (float*)&Kp[0][0][0];   // 16 KB combine scratch (dead K)
  float* const scrL = (float*)&Kr[0][0][0];   // 4 KB

#pragma unroll
  for (int seg = 0; seg < 2; ++seg) {
    const int qt = seg ? (15 - p) : p;
    const int qbase = qt * 64 + ws * 16;
    const int nit = qt + 1;
    const int L = (nit + 1) >> 1;   // per-group iteration count (uniform)

    short8 Qp[2], Qr[2];
    {
      const ushort* qp = Qb + ((size_t)b * S_LEN + qbase + i16) * D_MOD + h * DK + quad * 8;
      const ushort* qq = qraw + ((size_t)b * S_LEN + qbase + i16) * D_MOD + h * DK + quad * 8;
#pragma unroll
      for (int s = 0; s < 2; ++s) {
        Qp[s] = *(const short8*)(qp + s * 32);
        Qr[s] = *(const short8*)(qq + s * 32);
      }
    }

    floatx4 Oacc[4];
#pragma unroll
    for (int t4 = 0; t4 < 4; ++t4) Oacc[t4] = (floatx4)(0.f);
    float l_run[4] = {0.f, 0.f, 0.f, 0.f};

    // ---- prologue: stage this group's first tile (kt = grp) ----
    {
      short8 s0, s1, s2, s3, s4, s5;
      const bool have0 = (grp < nit);
      if (have0) {
        const size_t ko = (size_t)grp * 64;
        s0 = *(const short8*)(kpgB + ko * D_MOD);
        s1 = *(const short8*)(kpgB + ko * D_MOD + 32 * D_MOD);
        s2 = *(const short8*)(krgB + ko * D_MOD);
        s3 = *(const short8*)(krgB + ko * D_MOD + 32 * D_MOD);
        s4 = *(const short8*)(vgB + ko);
        s5 = *(const short8*)(vgB + ko + 32 * S_LEN);
      }
      __syncthreads();   // prior seg's LDS readers (incl. combine) done
      if (have0) {
        *(short8*)&Kp[grp][rr][pc] = s0;
        *(short8*)&Kp[grp][rr + 32][pc] = s1;
        *(short8*)&Kr[grp][rr][pc] = s2;
        *(short8*)&Kr[grp][rr + 32][pc] = s3;
        *(short8*)&Vc[grp][rr][pc] = s4;
        *(short8*)&Vc[grp][rr + 32][pc] = s5;
      }
      __syncthreads();
    }

    for (int it = 0; it < L; ++it) {
      const int kt = grp + 2 * it;
      const bool active = (kt < nit);          // group 1 may idle on last it
      const bool havenext = (kt + 2 < nit);
      const bool diag = (kt == qt);

      // ---- prefetch this group's next tile (global -> regs) ----
      short8 nk0, nk1, nr0, nr1, nv0, nv1;
      if (havenext) {
        const size_t ko = (size_t)(kt + 2) * 64;
        nk0 = *(const short8*)(kpgB + ko * D_MOD);
        nk1 = *(const short8*)(kpgB + ko * D_MOD + 32 * D_MOD);
        nr0 = *(const short8*)(krgB + ko * D_MOD);
        nr1 = *(const short8*)(krgB + ko * D_MOD + 32 * D_MOD);
        nv0 = *(const short8*)(vgB + ko);
        nv1 = *(const short8*)(vgB + ko + 32 * S_LEN);
      }

      if (active) {
        unsigned long long mw[4];
#pragma unroll
        for (int r = 0; r < 4; ++r)
          mw[r] = mbits[((size_t)b * S_LEN + qbase + quad * 4 + r) * 16 + kt];

        // ---- scores: 16 MFMAs from LDS ----
        floatx4 accp[4], accr[4];
#pragma unroll
        for (int t4 = 0; t4 < 4; ++t4) { accp[t4] = (floatx4)(0.f); accr[t4] = (floatx4)(0.f); }
#pragma unroll
        for (int s = 0; s < 2; ++s) {
          const int co = ((s * 4 + quad) ^ xi) * 8;
          short8 kp4[4], kr4[4];
#pragma unroll
          for (int t4 = 0; t4 < 4; ++t4) kp4[t4] = *(const short8*)&Kp[grp][t4 * 16 + i16][co];
#pragma unroll
          for (int t4 = 0; t4 < 4; ++t4) kr4[t4] = *(const short8*)&Kr[grp][t4 * 16 + i16][co];
#pragma unroll
          for (int t4 = 0; t4 < 4; ++t4)
            accp[t4] = __builtin_amdgcn_mfma_f32_16x16x32_bf16(Qp[s], kp4[t4], accp[t4], 0, 0, 0);
#pragma unroll
          for (int t4 = 0; t4 < 4; ++t4)
            accr[t4] = __builtin_amdgcn_mfma_f32_16x16x32_bf16(Qr[s], kr4[t4], accr[t4], 0, 0, 0);
        }

        // ---- combine + exp2, P -> per-wave LDS (truncation pack) ----
        const int k0g = kt * 64;
#pragma unroll
        for (int r = 0; r < 4; ++r) {
          const int qg = qbase + quad * 4 + r;
          const int prow = quad * 4 + r;
#pragma unroll
          for (int t4 = 0; t4 < 4; ++t4) {
            const float bitf = ((mw[r] >> (t4 * 16 + i16)) & 1ULL) ? c2 : 0.f;
            const float sv = accp[t4][r] * c1 + accr[t4][r] * bitf;
            float pv = __builtin_amdgcn_exp2f(sv);
            if (diag) {
              const int kg = k0g + t4 * 16 + i16;
              pv = (kg < qg) ? pv : 0.f;
            }
            l_run[r] += pv;
            const int kc = t4 * 2 + (i16 >> 3);
            Pl[w][prow][((kc ^ (prow & 7)) * 8) + (i16 & 7)] =
                (ushort)(__float_as_uint(pv) >> 16);
          }
        }

        // ---- PV: 8 MFMAs ----
#pragma unroll
        for (int s = 0; s < 2; ++s) {
          const int co = ((s * 4 + quad) ^ xi) * 8;
          short8 a = *(const short8*)&Pl[w][i16][co];
#pragma unroll
          for (int t4 = 0; t4 < 4; ++t4) {
            short8 bv8 = *(const short8*)&Vc[grp][t4 * 16 + i16][co];
            Oacc[t4] = __builtin_amdgcn_mfma_f32_16x16x32_bf16(a, bv8, Oacc[t4], 0, 0, 0);
          }
        }
      }

      __syncthreads();               // group's readers done with LDS tile
      if (havenext) {
        *(short8*)&Kp[grp][rr][pc] = nk0;
        *(short8*)&Kp[grp][rr + 32][pc] = nk1;
        *(short8*)&Kr[grp][rr][pc] = nr0;
        *(short8*)&Kr[grp][rr + 32][pc] = nr1;
        *(short8*)&Vc[grp][rr][pc] = nv0;
        *(short8*)&Vc[grp][rr + 32][pc] = nv1;
      }
      __syncthreads();               // next tile visible
    }

    // ---- cross-group combine (K buffers dead) + epilogue by group 0 ----
    if (grp == 1) {
#pragma unroll
      for (int t4 = 0; t4 < 4; ++t4)
#pragma unroll
        for (int r = 0; r < 4; ++r)
          scrO[(t4 * 4 + r) * 256 + tg] = Oacc[t4][r];
#pragma unroll
      for (int r = 0; r < 4; ++r) scrL[r * 256 + tg] = l_run[r];
    }
    __syncthreads();
    if (grp == 0) {
#pragma unroll
      for (int t4 = 0; t4 < 4; ++t4)
#pragma unroll
        for (int r = 0; r < 4; ++r)
          Oacc[t4][r] += scrO[(t4 * 4 + r) * 256 + tg];
#pragma unroll
      for (int r = 0; r < 4; ++r) {
        float l = l_run[r] + scrL[r * 256 + tg];
#pragma unroll
        for (int off = 1; off < 16; off <<= 1) l += __shfl_xor(l, off);
        const float inv = (l > 0.f) ? 1.f / l : 0.f;
        ushort* orow = Obf + ((size_t)b * S_LEN + qbase + quad * 4 + r) * D_MOD + h * DK;
#pragma unroll
        for (int t4 = 0; t4 < 4; ++t4)
          orow[t4 * 16 + i16] = f2bf(Oacc[t4][r] * inv);
      }
    }
    // next seg's prologue barrier orders scratch reads vs. re-staging
  }
}

// ---------------------------------------------------------------------------
// LayerNorm over D=512, one wave per row.
// ---------------------------------------------------------------------------
__global__ __launch_bounds__(256) void ln_kern(
    const float* __restrict__ X, const float* __restrict__ gw,
    const float* __restrict__ bw, float* __restrict__ out)
{
  const int row = blockIdx.x * 4 + (threadIdx.x >> 6);
  const int lane = threadIdx.x & 63;
  const int c = lane * 8;
  const float* xp = &X[(size_t)row * D_MOD + c];
  const float4 x0 = *(const float4*)xp;
  const float4 x1 = *(const float4*)(xp + 4);
  float xv[8] = {x0.x, x0.y, x0.z, x0.w, x1.x, x1.y, x1.z, x1.w};
  float sum = 0.f;
#pragma unroll
  for (int u = 0; u < 8; ++u) sum += xv[u];
#pragma unroll
  for (int off = 1; off < 64; off <<= 1) sum += __shfl_xor(sum, off, 64);
  const float mu = sum * (1.f / 512.f);
  float ss = 0.f;
#pragma unroll
  for (int u = 0; u < 8; ++u) { xv[u] -= mu; ss += xv[u] * xv[u]; }
#pragma unroll
  for (int off = 1; off < 64; off <<= 1) ss += __shfl_xor(ss, off, 64);
  const float rstd = rsqrtf(ss * (1.f / 512.f) + 1e-5f);
  const float4 g0 = *(const float4*)&gw[c];
  const float4 g1 = *(const float4*)&gw[c + 4];
  const float4 b0 = *(const float4*)&bw[c];
  const float4 b1 = *(const float4*)&bw[c + 4];
  float* op = &out[(size_t)row * D_MOD + c];
  *(float4*)op = make_float4(xv[0] * rstd * g0.x + b0.x,
                             xv[1] * rstd * g0.y + b0.y,
                             xv[2] * rstd * g0.z + b0.z,
                             xv[3] * rstd * g0.w + b0.w);
  *(float4*)(op + 4) = make_float4(xv[4] * rstd * g1.x + b1.x,
                                   xv[5] * rstd * g1.y + b1.y,
                                   xv[6] * rstd * g1.z + b1.z,
                                   xv[7] * rstd * g1.w + b1.w);
}

// ---------------------------------------------------------------------------
extern "C" void kernel_launch(void* const* d_in, const int* in_sizes, int n_in,
                              void* d_out, int out_size, void* d_ws, size_t ws_size,
                              hipStream_t stream)
{
  const float* q_in  = (const float*)d_in[0];
  const float* k_in  = (const float*)d_in[1];
  const float* v_in  = (const float*)d_in[2];
  const int*   smask = (const int*)d_in[3];
  const float* Wq = (const float*)d_in[4];
  const float* bq = (const float*)d_in[5];
  const float* Wv = (const float*)d_in[6];
  const float* bv = (const float*)d_in[7];
  const float* Wo = (const float*)d_in[8];
  const float* bo = (const float*)d_in[9];
  const float* gammas = (const float*)d_in[10];
  const float* ln_g = (const float*)d_in[11];
  const float* ln_b = (const float*)d_in[12];
  float* out = (float*)d_out;

  char* ws = (char*)d_ws;
  const size_t BF = (size_t)NB * S_LEN * D_MOD * sizeof(ushort);  // 8 MiB
  ushort* qr  = (ushort*)(ws);                 // [0,8M)
  ushort* kr  = (ushort*)(ws + BF);            // [8M,16M)
  ushort* vr  = (ushort*)(ws + 2 * BF);        // [16M,24M); Obf overlays after V-GEMM
  ushort* Obf = (ushort*)(ws + 2 * BF);
  ushort* Qbf = (ushort*)(ws + 3 * BF);        // [24M,32M)
  ushort* Kbf = (ushort*)(ws + 4 * BF);        // [32M,40M)
  ushort* Vt  = (ushort*)(ws + 5 * BF);        // [40M,48M)
  unsigned long long* mbits = (unsigned long long*)(ws + 6 * BF);      // 1 MiB
  ushort* Wqt = (ushort*)(ws + 6 * BF + (1 << 20));                    // 512 KiB
  ushort* Wvt = Wqt + 512 * 512;
  ushort* Wot = Wvt + 512 * 512;
  float*  X   = (float*)ws;                    // overlays qr+kr (dead after attn)

  const dim3 tb(256);

  prep_kern<<<dim3(2048, 4), tb, 0, stream>>>(q_in, k_in, v_in, smask,
                                              qr, kr, vr, mbits);
  wtrans3_kern<<<dim3(8, 8, 3), tb, 0, stream>>>(Wq, Wv, Wo, Wqt, Wvt, Wot);

  gemm_qkv_kern<<<dim3(64, 8, 3), tb, 0, stream>>>(qr, kr, vr, Wqt, Wvt,
                                                   bq, bv, Qbf, Kbf, Vt);

  attn_kern<<<dim3(64, 8), dim3(512), 0, stream>>>(Qbf, Kbf, Vt, qr, kr, mbits,
                                                   gammas, Obf);

  gemm_out_kern<<<dim3(64, 8), tb, 0, stream>>>(Obf, Wot, bo, q_in, X);
  ln_kern<<<2048, tb, 0, stream>>>(X, ln_g, ln_b, out);
}

// Round 3
// 229.694 us; speedup vs baseline: 1.4124x; 1.0567x over previous
//
#include <hip/hip_runtime.h>
#include <math.h>

#define S_LEN 1024
#define D_MOD 512
#define NH 8
#define DK 64
#define NB 8

typedef __attribute__((ext_vector_type(8))) short short8;   // 8 bf16 in 4 VGPRs
typedef __attribute__((ext_vector_type(4))) float floatx4;  // MFMA accumulator

union U8 { ushort u[8]; short8 v; };

__device__ __forceinline__ ushort f2bf(float x) {
  unsigned u = __float_as_uint(x);
  unsigned r = (u + 0x7fffu + ((u >> 16) & 1u)) >> 16;  // RNE
  return (ushort)r;
}

// ---------------------------------------------------------------------------
// Fused prep: y=0..2 -> fp32->bf16 convert of q/k/v; y=3 -> mask bit-pack.
// ---------------------------------------------------------------------------
__global__ __launch_bounds__(256) void prep_kern(
    const float* __restrict__ q, const float* __restrict__ k,
    const float* __restrict__ v, const int* __restrict__ smask,
    ushort* __restrict__ qo, ushort* __restrict__ ko,
    ushort* __restrict__ vo, unsigned long long* __restrict__ mb)
{
  const int y = blockIdx.y;
  const int t = threadIdx.x;
  if (y < 3) {
    const float* src = (y == 0) ? q : (y == 1) ? k : v;
    ushort* dst = (y == 0) ? qo : (y == 1) ? ko : vo;
    const int i = blockIdx.x * 256 + t;
    const float4 a = *((const float4*)src + i * 2);
    const float4 b = *((const float4*)src + i * 2 + 1);
    U8 o;
    o.u[0] = f2bf(a.x); o.u[1] = f2bf(a.y); o.u[2] = f2bf(a.z); o.u[3] = f2bf(a.w);
    o.u[4] = f2bf(b.x); o.u[5] = f2bf(b.y); o.u[6] = f2bf(b.z); o.u[7] = f2bf(b.w);
    *(short8*)(dst + (size_t)i * 8) = o.v;
  } else {
    const int row = blockIdx.x * 4 + (t >> 6);
    const int lane = t & 63;
    const int* p = smask + (size_t)row * S_LEN;
    unsigned long long mine = 0;
#pragma unroll
    for (int r = 0; r < 16; ++r) {
      int m = p[r * 64 + lane];
      unsigned long long w = __ballot(m != 0);
      if (lane == r) mine = w;
    }
    if (lane < 16) mb[(size_t)row * 16 + lane] = mine;
  }
}

// ---------------------------------------------------------------------------
// Weight transpose+convert: W fp32 [512(k),512(n)] -> Wt bf16 [512(n),512(k)]
// ---------------------------------------------------------------------------
__global__ __launch_bounds__(256) void wtrans3_kern(
    const float* __restrict__ W0, const float* __restrict__ W1,
    const float* __restrict__ W2, ushort* __restrict__ T0,
    ushort* __restrict__ T1, ushort* __restrict__ T2)
{
  const int z = blockIdx.z;
  const float* W = (z == 0) ? W0 : (z == 1) ? W1 : W2;
  ushort* Wt = (z == 0) ? T0 : (z == 1) ? T1 : T2;
  __shared__ __align__(16) ushort tile[64][72];
  const int t = threadIdx.x;
  const int n0 = blockIdx.x * 64;
  const int k0 = blockIdx.y * 64;
  {
    const int r = t >> 2;
    const int c0 = (t & 3) * 16;
    const float* p = &W[(size_t)(k0 + r) * 512 + n0 + c0];
#pragma unroll
    for (int j = 0; j < 16; ++j) tile[r][c0 + j] = f2bf(p[j]);
  }
  __syncthreads();
  {
    const int c = t >> 2;
    const int kg = (t & 3) * 16;
    U8 lo, hi;
#pragma unroll
    for (int j = 0; j < 8; ++j) lo.u[j] = tile[kg + j][c];
#pragma unroll
    for (int j = 0; j < 8; ++j) hi.u[j] = tile[kg + 8 + j][c];
    ushort* q = &Wt[(size_t)(n0 + c) * 512 + k0 + kg];
    *(short8*)q = lo.v;
    *(short8*)(q + 8) = hi.v;
  }
}

// ---------------------------------------------------------------------------
// bf16 MFMA GEMM, WIDENED to 128m x 128n block (R3): double-buffered B-tile
// (128n x 64k, XOR-swizzled, 32 KB LDS), A wave-private in regs with
// depth-2 prefetch ring (32 MFMAs/iter covers latency). 4 waves, each
// 32m x 128n (acc 2x8 frags = 64 f32). BK=64, 8 iters, 1 barrier/iter.
// grid.y halves (8->4): A re-streamed 4x instead of 8x, half the barriers
// per output element. z=0/1: bf16 row-major out. z=2: Vt [B,H,64,S].
// ---------------------------------------------------------------------------
__global__ __launch_bounds__(256) void gemm_qkv_kern(
    const ushort* __restrict__ qr, const ushort* __restrict__ kr,
    const ushort* __restrict__ vr, const ushort* __restrict__ Wqt,
    const ushort* __restrict__ Wvt, const float* __restrict__ bq,
    const float* __restrict__ bv, ushort* __restrict__ Qo,
    ushort* __restrict__ Ko, ushort* __restrict__ VtO)
{
  __shared__ __align__(16) ushort Bl[2][128][64];  // 32 KB

  const int z = blockIdx.z;
  const ushort* A = (z == 0) ? qr : (z == 1) ? kr : vr;
  const ushort* Wt = (z == 2) ? Wvt : Wqt;
  const float* bias = (z == 2) ? bv : bq;

  const int t = threadIdx.x;
  const int w = t >> 6;
  const int lane = t & 63;
  const int quad = lane >> 4;
  const int i16 = lane & 15;
  const int mbase = blockIdx.x * 128 + w * 32;
  const int nbase = blockIdx.y * 128;

  // staging geometry: thread -> B row sr = t>>1, k-half (t&1), 4 chunks of 8
  const int sr = t >> 1;
  const int lc0 = (t & 1) * 4;
  int sp[4];
#pragma unroll
  for (int j = 0; j < 4; ++j) sp[j] = (((lc0 + j) ^ (sr & 7)) * 8);
  const ushort* Bg = Wt + (size_t)(nbase + sr) * 512 + (t & 1) * 32;
  const int xb = i16 & 7;

  const ushort* Ap = A + (size_t)(mbase + i16) * 512 + quad * 8;

  floatx4 acc[2][8];
#pragma unroll
  for (int mi = 0; mi < 2; ++mi)
#pragma unroll
    for (int ni = 0; ni < 8; ++ni) acc[mi][ni] = (floatx4)(0.f);

  short8 areg[2][2][2];  // ring, mi, kc
#pragma unroll
  for (int mi = 0; mi < 2; ++mi)
#pragma unroll
    for (int kc = 0; kc < 2; ++kc)
      areg[0][mi][kc] = *(const short8*)(Ap + kc * 32 + mi * 16 * 512);

  // prologue: stage B tile 0
  {
    short8 b[4];
#pragma unroll
    for (int j = 0; j < 4; ++j) b[j] = *(const short8*)(Bg + j * 8);
#pragma unroll
    for (int j = 0; j < 4; ++j) *(short8*)&Bl[0][sr][sp[j]] = b[j];
    __syncthreads();
  }

#pragma unroll
  for (int kt = 0; kt < 8; ++kt) {
    const int cb = kt & 1;
    short8 nb[4];
    if (kt < 7) {
#pragma unroll
      for (int j = 0; j < 4; ++j)
        nb[j] = *(const short8*)(Bg + (kt + 1) * 64 + j * 8);
#pragma unroll
      for (int mi = 0; mi < 2; ++mi)
#pragma unroll
        for (int kc = 0; kc < 2; ++kc)
          areg[(kt + 1) & 1][mi][kc] =
              *(const short8*)(Ap + (kt + 1) * 64 + kc * 32 + mi * 16 * 512);
    }
#pragma unroll
    for (int kc = 0; kc < 2; ++kc) {
      short8 bf8[8];
#pragma unroll
      for (int ni = 0; ni < 8; ++ni)
        bf8[ni] = *(const short8*)&Bl[cb][ni * 16 + i16][((kc * 4 + quad) ^ xb) * 8];
#pragma unroll
      for (int mi = 0; mi < 2; ++mi)
#pragma unroll
        for (int ni = 0; ni < 8; ++ni)
          acc[mi][ni] = __builtin_amdgcn_mfma_f32_16x16x32_bf16(
              areg[kt & 1][mi][kc], bf8[ni], acc[mi][ni], 0, 0, 0);
    }
    if (kt < 7) {
#pragma unroll
      for (int j = 0; j < 4; ++j) *(short8*)&Bl[cb ^ 1][sr][sp[j]] = nb[j];
      __syncthreads();
    }
  }

  float bv8[8];
#pragma unroll
  for (int ni = 0; ni < 8; ++ni) bv8[ni] = bias[nbase + ni * 16 + i16];

  if (z < 2) {
    ushort* C = (z == 0) ? Qo : Ko;
#pragma unroll
    for (int mi = 0; mi < 2; ++mi)
#pragma unroll
      for (int ni = 0; ni < 8; ++ni)
#pragma unroll
        for (int r = 0; r < 4; ++r) {
          const int m = mbase + mi * 16 + quad * 4 + r;
          const int n = nbase + ni * 16 + i16;
          C[(size_t)m * 512 + n] = f2bf(acc[mi][ni][r] + bv8[ni]);
        }
  } else {
#pragma unroll
    for (int mi = 0; mi < 2; ++mi)
#pragma unroll
      for (int ni = 0; ni < 8; ++ni) {
        const int m = mbase + mi * 16 + quad * 4;
        const int b = m >> 10;
        const int s = m & 1023;
        const int n = nbase + ni * 16 + i16;
        const int h = n >> 6;
        const int c = n & 63;
        ushort4 pk;
        pk.x = f2bf(acc[mi][ni][0] + bv8[ni]);
        pk.y = f2bf(acc[mi][ni][1] + bv8[ni]);
        pk.z = f2bf(acc[mi][ni][2] + bv8[ni]);
        pk.w = f2bf(acc[mi][ni][3] + bv8[ni]);
        *(ushort4*)(VtO + (((size_t)b * NH + h) * DK + c) * S_LEN + s) = pk;
      }
  }
}

// ---------------------------------------------------------------------------
// Output GEMM: X = Obf @ Wot^T + bo + R (fp32 out). 128x128 tile (R3).
// ---------------------------------------------------------------------------
__global__ __launch_bounds__(256) void gemm_out_kern(
    const ushort* __restrict__ A, const ushort* __restrict__ Wt,
    const float* __restrict__ bias, const float* __restrict__ R,
    float* __restrict__ X)
{
  __shared__ __align__(16) ushort Bl[2][128][64];  // 32 KB

  const int t = threadIdx.x;
  const int w = t >> 6;
  const int lane = t & 63;
  const int quad = lane >> 4;
  const int i16 = lane & 15;
  const int mbase = blockIdx.x * 128 + w * 32;
  const int nbase = blockIdx.y * 128;

  const int sr = t >> 1;
  const int lc0 = (t & 1) * 4;
  int sp[4];
#pragma unroll
  for (int j = 0; j < 4; ++j) sp[j] = (((lc0 + j) ^ (sr & 7)) * 8);
  const ushort* Bg = Wt + (size_t)(nbase + sr) * 512 + (t & 1) * 32;
  const int xb = i16 & 7;

  const ushort* Ap = A + (size_t)(mbase + i16) * 512 + quad * 8;

  floatx4 acc[2][8];
#pragma unroll
  for (int mi = 0; mi < 2; ++mi)
#pragma unroll
    for (int ni = 0; ni < 8; ++ni) acc[mi][ni] = (floatx4)(0.f);

  short8 areg[2][2][2];
#pragma unroll
  for (int mi = 0; mi < 2; ++mi)
#pragma unroll
    for (int kc = 0; kc < 2; ++kc)
      areg[0][mi][kc] = *(const short8*)(Ap + kc * 32 + mi * 16 * 512);

  {
    short8 b[4];
#pragma unroll
    for (int j = 0; j < 4; ++j) b[j] = *(const short8*)(Bg + j * 8);
#pragma unroll
    for (int j = 0; j < 4; ++j) *(short8*)&Bl[0][sr][sp[j]] = b[j];
    __syncthreads();
  }

#pragma unroll
  for (int kt = 0; kt < 8; ++kt) {
    const int cb = kt & 1;
    short8 nb[4];
    if (kt < 7) {
#pragma unroll
      for (int j = 0; j < 4; ++j)
        nb[j] = *(const short8*)(Bg + (kt + 1) * 64 + j * 8);
#pragma unroll
      for (int mi = 0; mi < 2; ++mi)
#pragma unroll
        for (int kc = 0; kc < 2; ++kc)
          areg[(kt + 1) & 1][mi][kc] =
              *(const short8*)(Ap + (kt + 1) * 64 + kc * 32 + mi * 16 * 512);
    }
#pragma unroll
    for (int kc = 0; kc < 2; ++kc) {
      short8 bf8[8];
#pragma unroll
      for (int ni = 0; ni < 8; ++ni)
        bf8[ni] = *(const short8*)&Bl[cb][ni * 16 + i16][((kc * 4 + quad) ^ xb) * 8];
#pragma unroll
      for (int mi = 0; mi < 2; ++mi)
#pragma unroll
        for (int ni = 0; ni < 8; ++ni)
          acc[mi][ni] = __builtin_amdgcn_mfma_f32_16x16x32_bf16(
              areg[kt & 1][mi][kc], bf8[ni], acc[mi][ni], 0, 0, 0);
    }
    if (kt < 7) {
#pragma unroll
      for (int j = 0; j < 4; ++j) *(short8*)&Bl[cb ^ 1][sr][sp[j]] = nb[j];
      __syncthreads();
    }
  }

  float bv8[8];
#pragma unroll
  for (int ni = 0; ni < 8; ++ni) bv8[ni] = bias[nbase + ni * 16 + i16];
#pragma unroll
  for (int mi = 0; mi < 2; ++mi)
#pragma unroll
    for (int ni = 0; ni < 8; ++ni)
#pragma unroll
      for (int r = 0; r < 4; ++r) {
        const int m = mbase + mi * 16 + quad * 4 + r;
        const int n = nbase + ni * 16 + i16;
        X[(size_t)m * 512 + n] = acc[mi][ni][r] + bv8[ni] + R[(size_t)m * 512 + n];
      }
}

// ---------------------------------------------------------------------------
// MFMA dual-score causal attention (R0 structure, reverted in R3):
// DOUBLE-BUFFERED LDS staging of K/Kr/V, 4 waves/block, 256 threads.
// 1 barrier/iter. Diagonal-only causal masking. exp2 with folded ln2.
// Block (bh, p): q-tiles p and 15-p -> 17 iters/block.
// R1/R2 post-mortem: occupancy is register-bound (~2 waves/SIMD incl. acc
// regs); k-split 8-wave blocks got 1 block/CU and regressed 42->53 us.
// This structure is the measured optimum at the occupancy ceiling.
// ---------------------------------------------------------------------------
__global__ __launch_bounds__(256) void attn_kern(
    const ushort* __restrict__ Qb, const ushort* __restrict__ Kb,
    const ushort* __restrict__ VtG, const ushort* __restrict__ qraw,
    const ushort* __restrict__ kraw,
    const unsigned long long* __restrict__ mbits,
    const float* __restrict__ gammas, ushort* __restrict__ Obf)
{
  __shared__ __align__(16) ushort Kp[2][64][64];
  __shared__ __align__(16) ushort Kr[2][64][64];
  __shared__ __align__(16) ushort Vc[2][64][64];
  __shared__ __align__(16) ushort Pl[4][16][64];

  const int t = threadIdx.x;
  const int w = t >> 6;
  const int lane = t & 63;
  const int quad = lane >> 4;
  const int i16 = lane & 15;
  const int bh = blockIdx.x;          // 0..63
  const int b = bh >> 3;
  const int h = bh & 7;
  const int p = blockIdx.y;           // 0..7

  const float gam = gammas[h];
  float te = __expf(-log1pf(__expf(gam)));
  te = fminf(fmaxf(te, 1e-5f), 1e5f);
  const float c1 = 0.125f * 1.44269504f;
  const float c2 = te * 0.044194173824159216f * 1.44269504f;

  const int xi = i16 & 7;
  const int rr = t >> 3;              // staging row 0..31
  const int lc = t & 7;
  const int pc = ((lc ^ (rr & 7)) * 8);

  const ushort* kpgB = Kb + ((size_t)b * S_LEN + rr) * D_MOD + h * DK + lc * 8;
  const ushort* krgB = kraw + ((size_t)b * S_LEN + rr) * D_MOD + h * DK + lc * 8;
  const ushort* vgB  = VtG + ((size_t)bh * DK + rr) * S_LEN + lc * 8;

#pragma unroll
  for (int seg = 0; seg < 2; ++seg) {
    const int qt = seg ? (15 - p) : p;
    const int qbase = qt * 64 + w * 16;

    short8 Qp[2], Qr[2];
    {
      const ushort* qp = Qb + ((size_t)b * S_LEN + qbase + i16) * D_MOD + h * DK + quad * 8;
      const ushort* qq = qraw + ((size_t)b * S_LEN + qbase + i16) * D_MOD + h * DK + quad * 8;
#pragma unroll
      for (int s = 0; s < 2; ++s) {
        Qp[s] = *(const short8*)(qp + s * 32);
        Qr[s] = *(const short8*)(qq + s * 32);
      }
    }

    floatx4 Oacc[4];
#pragma unroll
    for (int t4 = 0; t4 < 4; ++t4) Oacc[t4] = (floatx4)(0.f);
    float l_run[4] = {0.f, 0.f, 0.f, 0.f};

    const int nit = qt + 1;

    // ---- prologue: stage tile 0 into buffer 0 ----
    {
      short8 k0v0 = *(const short8*)kpgB;
      short8 k0v1 = *(const short8*)(kpgB + 32 * D_MOD);
      short8 r0v0 = *(const short8*)krgB;
      short8 r0v1 = *(const short8*)(krgB + 32 * D_MOD);
      short8 v0v0 = *(const short8*)vgB;
      short8 v0v1 = *(const short8*)(vgB + 32 * S_LEN);
      __syncthreads();   // prior seg's readers done
      *(short8*)&Kp[0][rr][pc] = k0v0;
      *(short8*)&Kp[0][rr + 32][pc] = k0v1;
      *(short8*)&Kr[0][rr][pc] = r0v0;
      *(short8*)&Kr[0][rr + 32][pc] = r0v1;
      *(short8*)&Vc[0][rr][pc] = v0v0;
      *(short8*)&Vc[0][rr + 32][pc] = v0v1;
      __syncthreads();
    }

    for (int kt = 0; kt < nit; ++kt) {
      const int cb = kt & 1;
      const bool havenext = (kt + 1 < nit);
      const bool diag = (kt == qt);

      // ---- prefetch next tile (global -> regs), lands during compute ----
      short8 nk0, nk1, nr0, nr1, nv0, nv1;
      if (havenext) {
        const size_t ko = (size_t)(kt + 1) * 64;
        nk0 = *(const short8*)(kpgB + ko * D_MOD);
        nk1 = *(const short8*)(kpgB + ko * D_MOD + 32 * D_MOD);
        nr0 = *(const short8*)(krgB + ko * D_MOD);
        nr1 = *(const short8*)(krgB + ko * D_MOD + 32 * D_MOD);
        nv0 = *(const short8*)(vgB + ko);
        nv1 = *(const short8*)(vgB + ko + 32 * S_LEN);
      }

      unsigned long long mw[4];
#pragma unroll
      for (int r = 0; r < 4; ++r)
        mw[r] = mbits[((size_t)b * S_LEN + qbase + quad * 4 + r) * 16 + kt];

      // ---- scores: 16 MFMAs from LDS ----
      floatx4 accp[4], accr[4];
#pragma unroll
      for (int t4 = 0; t4 < 4; ++t4) { accp[t4] = (floatx4)(0.f); accr[t4] = (floatx4)(0.f); }
#pragma unroll
      for (int s = 0; s < 2; ++s) {
        const int co = ((s * 4 + quad) ^ xi) * 8;
        short8 kp4[4], kr4[4];
#pragma unroll
        for (int t4 = 0; t4 < 4; ++t4) kp4[t4] = *(const short8*)&Kp[cb][t4 * 16 + i16][co];
#pragma unroll
        for (int t4 = 0; t4 < 4; ++t4) kr4[t4] = *(const short8*)&Kr[cb][t4 * 16 + i16][co];
#pragma unroll
        for (int t4 = 0; t4 < 4; ++t4)
          accp[t4] = __builtin_amdgcn_mfma_f32_16x16x32_bf16(Qp[s], kp4[t4], accp[t4], 0, 0, 0);
#pragma unroll
        for (int t4 = 0; t4 < 4; ++t4)
          accr[t4] = __builtin_amdgcn_mfma_f32_16x16x32_bf16(Qr[s], kr4[t4], accr[t4], 0, 0, 0);
      }

      // ---- combine + exp2, P -> per-wave LDS (truncation pack) ----
      const int k0g = kt * 64;
#pragma unroll
      for (int r = 0; r < 4; ++r) {
        const int qg = qbase + quad * 4 + r;
        const int prow = quad * 4 + r;
#pragma unroll
        for (int t4 = 0; t4 < 4; ++t4) {
          const float bitf = ((mw[r] >> (t4 * 16 + i16)) & 1ULL) ? c2 : 0.f;
          const float sv = accp[t4][r] * c1 + accr[t4][r] * bitf;
          float pv = __builtin_amdgcn_exp2f(sv);
          if (diag) {
            const int kg = k0g + t4 * 16 + i16;
            pv = (kg < qg) ? pv : 0.f;
          }
          l_run[r] += pv;
          const int kc = t4 * 2 + (i16 >> 3);
          Pl[w][prow][((kc ^ (prow & 7)) * 8) + (i16 & 7)] =
              (ushort)(__float_as_uint(pv) >> 16);
        }
      }

      // ---- PV: 8 MFMAs ----
#pragma unroll
      for (int s = 0; s < 2; ++s) {
        const int co = ((s * 4 + quad) ^ xi) * 8;
        short8 a = *(const short8*)&Pl[w][i16][co];
#pragma unroll
        for (int t4 = 0; t4 < 4; ++t4) {
          short8 bv8 = *(const short8*)&Vc[cb][t4 * 16 + i16][co];
          Oacc[t4] = __builtin_amdgcn_mfma_f32_16x16x32_bf16(a, bv8, Oacc[t4], 0, 0, 0);
        }
      }

      // ---- write next tile into the other buffer ----
      if (havenext) {
        *(short8*)&Kp[cb ^ 1][rr][pc] = nk0;
        *(short8*)&Kp[cb ^ 1][rr + 32][pc] = nk1;
        *(short8*)&Kr[cb ^ 1][rr][pc] = nr0;
        *(short8*)&Kr[cb ^ 1][rr + 32][pc] = nr1;
        *(short8*)&Vc[cb ^ 1][rr][pc] = nv0;
        *(short8*)&Vc[cb ^ 1][rr + 32][pc] = nv1;
        __syncthreads();
      }
    }

    // ---- epilogue ----
#pragma unroll
    for (int r = 0; r < 4; ++r) {
      float l = l_run[r];
#pragma unroll
      for (int off = 1; off < 16; off <<= 1) l += __shfl_xor(l, off);
      const float inv = (l > 0.f) ? 1.f / l : 0.f;
      ushort* orow = Obf + ((size_t)b * S_LEN + qbase + quad * 4 + r) * D_MOD + h * DK;
#pragma unroll
      for (int t4 = 0; t4 < 4; ++t4)
        orow[t4 * 16 + i16] = f2bf(Oacc[t4][r] * inv);
    }
  }
}

// ---------------------------------------------------------------------------
// LayerNorm over D=512, one wave per row.
// ---------------------------------------------------------------------------
__global__ __launch_bounds__(256) void ln_kern(
    const float* __restrict__ X, const float* __restrict__ gw,
    const float* __restrict__ bw, float* __restrict__ out)
{
  const int row = blockIdx.x * 4 + (threadIdx.x >> 6);
  const int lane = threadIdx.x & 63;
  const int c = lane * 8;
  const float* xp = &X[(size_t)row * D_MOD + c];
  const float4 x0 = *(const float4*)xp;
  const float4 x1 = *(const float4*)(xp + 4);
  float xv[8] = {x0.x, x0.y, x0.z, x0.w, x1.x, x1.y, x1.z, x1.w};
  float sum = 0.f;
#pragma unroll
  for (int u = 0; u < 8; ++u) sum += xv[u];
#pragma unroll
  for (int off = 1; off < 64; off <<= 1) sum += __shfl_xor(sum, off, 64);
  const float mu = sum * (1.f / 512.f);
  float ss = 0.f;
#pragma unroll
  for (int u = 0; u < 8; ++u) { xv[u] -= mu; ss += xv[u] * xv[u]; }
#pragma unroll
  for (int off = 1; off < 64; off <<= 1) ss += __shfl_xor(ss, off, 64);
  const float rstd = rsqrtf(ss * (1.f / 512.f) + 1e-5f);
  const float4 g0 = *(const float4*)&gw[c];
  const float4 g1 = *(const float4*)&gw[c + 4];
  const float4 b0 = *(const float4*)&bw[c];
  const float4 b1 = *(const float4*)&bw[c + 4];
  float* op = &out[(size_t)row * D_MOD + c];
  *(float4*)op = make_float4(xv[0] * rstd * g0.x + b0.x,
                             xv[1] * rstd * g0.y + b0.y,
                             xv[2] * rstd * g0.z + b0.z,
                             xv[3] * rstd * g0.w + b0.w);
  *(float4*)(op + 4) = make_float4(xv[4] * rstd * g1.x + b1.x,
                                   xv[5] * rstd * g1.y + b1.y,
                                   xv[6] * rstd * g1.z + b1.z,
                                   xv[7] * rstd * g1.w + b1.w);
}

// ---------------------------------------------------------------------------
extern "C" void kernel_launch(void* const* d_in, const int* in_sizes, int n_in,
                              void* d_out, int out_size, void* d_ws, size_t ws_size,
                              hipStream_t stream)
{
  const float* q_in  = (const float*)d_in[0];
  const float* k_in  = (const float*)d_in[1];
  const float* v_in  = (const float*)d_in[2];
  const int*   smask = (const int*)d_in[3];
  const float* Wq = (const float*)d_in[4];
  const float* bq = (const float*)d_in[5];
  const float* Wv = (const float*)d_in[6];
  const float* bv = (const float*)d_in[7];
  const float* Wo = (const float*)d_in[8];
  const float* bo = (const float*)d_in[9];
  const float* gammas = (const float*)d_in[10];
  const float* ln_g = (const float*)d_in[11];
  const float* ln_b = (const float*)d_in[12];
  float* out = (float*)d_out;

  char* ws = (char*)d_ws;
  const size_t BF = (size_t)NB * S_LEN * D_MOD * sizeof(ushort);  // 8 MiB
  ushort* qr  = (ushort*)(ws);                 // [0,8M)
  ushort* kr  = (ushort*)(ws + BF);            // [8M,16M)
  ushort* vr  = (ushort*)(ws + 2 * BF);        // [16M,24M); Obf overlays after V-GEMM
  ushort* Obf = (ushort*)(ws + 2 * BF);
  ushort* Qbf = (ushort*)(ws + 3 * BF);        // [24M,32M)
  ushort* Kbf = (ushort*)(ws + 4 * BF);        // [32M,40M)
  ushort* Vt  = (ushort*)(ws + 5 * BF);        // [40M,48M)
  unsigned long long* mbits = (unsigned long long*)(ws + 6 * BF);      // 1 MiB
  ushort* Wqt = (ushort*)(ws + 6 * BF + (1 << 20));                    // 512 KiB
  ushort* Wvt = Wqt + 512 * 512;
  ushort* Wot = Wvt + 512 * 512;
  float*  X   = (float*)ws;                    // overlays qr+kr (dead after attn)

  const dim3 tb(256);

  prep_kern<<<dim3(2048, 4), tb, 0, stream>>>(q_in, k_in, v_in, smask,
                                              qr, kr, vr, mbits);
  wtrans3_kern<<<dim3(8, 8, 3), tb, 0, stream>>>(Wq, Wv, Wo, Wqt, Wvt, Wot);

  gemm_qkv_kern<<<dim3(64, 4, 3), tb, 0, stream>>>(qr, kr, vr, Wqt, Wvt,
                                                   bq, bv, Qbf, Kbf, Vt);

  attn_kern<<<dim3(64, 8), tb, 0, stream>>>(Qbf, Kbf, Vt, qr, kr, mbits,
                                            gammas, Obf);

  gemm_out_kern<<<dim3(64, 4), tb, 0, stream>>>(Obf, Wot, bo, q_in, X);
  ln_kern<<<2048, tb, 0, stream>>>(X, ln_g, ln_b, out);
}